// Round 18
// baseline (427.661 us; speedup 1.0000x reference)
//
#include <hip/hip_runtime.h>

#define N_NODES 100000
#define N_EDGES 1600000
#define F_IN    32
#define HD      64
#define EPS     1e-5f
#define NSHADOW 64
#define NP      196      // partitions (512 nodes each)
#define PWS     9        // partition width shift
#define NB1     250      // blocks in pass1/2
#define EPB     6400     // edges per block (250*6400 = E exactly)
#define NPLANE  (N_NODES * 8)   // uints per fp8 column-plane

typedef __attribute__((ext_vector_type(8))) short short8v;
typedef __attribute__((ext_vector_type(4))) float f32x4;
typedef __attribute__((ext_vector_type(2))) float f32x2;

__device__ __forceinline__ unsigned bf16r(float f) {
    unsigned u = __float_as_uint(f);
    return (u + 0x7fffu + ((u >> 16) & 1u)) >> 16;
}
__device__ __forceinline__ unsigned pack2(float lo, float hi) {
    return bf16r(lo) | (bf16r(hi) << 16);
}
__device__ __forceinline__ float unlo(unsigned u) { return __uint_as_float(u << 16); }
__device__ __forceinline__ float unhi(unsigned u) { return __uint_as_float(u & 0xffff0000u); }

__device__ __forceinline__ unsigned pack_fp8x4(float a, float b, float c, float d) {
    int v = __builtin_amdgcn_cvt_pk_fp8_f32(a, b, 0, false);
    v = __builtin_amdgcn_cvt_pk_fp8_f32(c, d, v, true);
    return (unsigned)v;
}

// ---------------- edge-index dtype probe ----------------
__global__ void k_detect(const int* __restrict__ ei, int* __restrict__ flag) {
    if (threadIdx.x == 0 && blockIdx.x == 0) {
        int all_zero = 1;
        for (int k = 0; k < 64; ++k)
            if (ei[2 * k + 1] != 0) { all_zero = 0; break; }
        *flag = all_zero;   // 1 -> int64 layout, 0 -> int32 layout
    }
}

__device__ __forceinline__ int load_src(const int* ei, int e, int is64) {
    return is64 ? ei[2 * e] : ei[e];
}
__device__ __forceinline__ int load_dst(const int* ei, int e, int is64) {
    return is64 ? ei[2 * (N_EDGES + e)] : ei[N_EDGES + e];
}

// ---------------- CSR build pass 1: per-(block,partition) histogram ----------------
__global__ void __launch_bounds__(256)
k_p1_hist(const int* __restrict__ ei, const int* __restrict__ flag, int* __restrict__ hcnt) {
    __shared__ int hist[NP];
    int t = threadIdx.x, b = blockIdx.x;
    if (t < NP) hist[t] = 0;
    __syncthreads();
    int is64 = *flag;
#pragma unroll 5
    for (int i = 0; i < 25; ++i) {
        int e = b * EPB + i * 256 + t;
        int d = load_dst(ei, e, is64);
        atomicAdd(&hist[d >> PWS], 1);
    }
    __syncthreads();
    if (t < NP) hcnt[t * NB1 + b] = hist[t];
}

// ---------------- per-partition exclusive scan over blocks ----------------
__global__ void k_p2scan(const int* __restrict__ hcnt, int* __restrict__ off_bp,
                         int* __restrict__ ptotal) {
    __shared__ int ls[256];
    int t = threadIdx.x, p = blockIdx.x;
    int v = (t < NB1) ? hcnt[p * NB1 + t] : 0;
    ls[t] = v;
    __syncthreads();
    for (int off = 1; off < 256; off <<= 1) {
        int u = (t >= off) ? ls[t - off] : 0;
        __syncthreads();
        ls[t] += u;
        __syncthreads();
    }
    if (t < NB1) off_bp[p * NB1 + t] = ls[t] - v;
    if (t == 255) ptotal[p] = ls[255];
}

// ---------------- scan partition totals -> pbase ----------------
__global__ void k_p3scan(const int* __restrict__ ptotal, int* __restrict__ pbase) {
    __shared__ int ls[256];
    int t = threadIdx.x;
    int v = (t < NP) ? ptotal[t] : 0;
    ls[t] = v;
    __syncthreads();
    for (int off = 1; off < 256; off <<= 1) {
        int u = (t >= off) ? ls[t - off] : 0;
        __syncthreads();
        ls[t] += u;
        __syncthreads();
    }
    if (t < NP) pbase[t] = ls[t] - v;
}

// ---------------- scatter edge records into partition buffer ----------------
__global__ void __launch_bounds__(256)
k_p2_scatter(const int* __restrict__ ei, const int* __restrict__ flag,
             const int* __restrict__ off_bp, const int* __restrict__ pbase,
             uint2* __restrict__ part_buf) {
    __shared__ int cursor[NP];
    int t = threadIdx.x, b = blockIdx.x;
    if (t < NP) cursor[t] = pbase[t] + off_bp[t * NB1 + b];
    __syncthreads();
    int is64 = *flag;
#pragma unroll 5
    for (int i = 0; i < 25; ++i) {
        int e = b * EPB + i * 256 + t;
        int s = load_src(ei, e, is64);
        int d = load_dst(ei, e, is64);
        int slot = atomicAdd(&cursor[d >> PWS], 1);
        part_buf[slot] = make_uint2((unsigned)s, (unsigned)d);
    }
}

// ---------------- fused pass 3: hist -> LDS scan -> row_start+dinv -> csr place ----------------
__global__ void __launch_bounds__(256)
k_p3_build(const uint2* __restrict__ part_buf, const int* __restrict__ pbase,
           const int* __restrict__ ptotal, int* __restrict__ row_start,
           float* __restrict__ dinv, int* __restrict__ csr_src) {
    __shared__ int hist[512];
    __shared__ int s2[256];
    __shared__ int cur[512];
    int t = threadIdx.x, p = blockIdx.x;
    hist[t] = 0; hist[t + 256] = 0;
    __syncthreads();
    int beg = pbase[p], cnt = ptotal[p];
    for (int r = t; r < cnt; r += 256)
        atomicAdd(&hist[part_buf[beg + r].y & 511], 1);
    __syncthreads();
    int d0 = hist[2 * t], d1 = hist[2 * t + 1];
    s2[t] = d0 + d1;
    __syncthreads();
    for (int off = 1; off < 256; off <<= 1) {
        int u = (t >= off) ? s2[t - off] : 0;
        __syncthreads();
        s2[t] += u;
        __syncthreads();
    }
    int ex = (t == 0) ? 0 : s2[t - 1];
    int rs0 = beg + ex, rs1 = beg + ex + d0;
    int n0 = (p << PWS) + 2 * t;
    if (n0 < N_NODES)     { row_start[n0]     = rs0; dinv[n0]     = rsqrtf((float)d0 + 1.f); }
    if (n0 + 1 < N_NODES) { row_start[n0 + 1] = rs1; dinv[n0 + 1] = rsqrtf((float)d1 + 1.f); }
    cur[2 * t] = rs0; cur[2 * t + 1] = rs1;
    if (p == NP - 1 && t == 0) row_start[N_NODES] = N_EDGES;
    __syncthreads();
    for (int r = t; r < cnt; r += 256) {
        uint2 rec = part_buf[beg + r];
        int slot = atomicAdd(&cur[rec.y & 511], 1);
        csr_src[slot] = (int)rec.x;
    }
}

// ---------------- node embedding: hb = bf16(x @ W_embed + b) ----------------
__global__ void k_embed(const float* __restrict__ x, const float* __restrict__ W,
                        const float* __restrict__ b, unsigned* __restrict__ hb) {
    __shared__ float Ws[F_IN * HD];
    __shared__ float xs[4 * F_IN];
    int t = threadIdx.x;
    for (int i = t; i < F_IN * HD; i += 256) Ws[i] = W[i];
    if (t < 4 * F_IN) {
        int r = t >> 5, c = t & 31;
        int node = blockIdx.x * 4 + r;
        xs[t] = (node < N_NODES) ? x[node * F_IN + c] : 0.f;
    }
    __syncthreads();
    int r = t >> 6, j = t & 63;
    int node = blockIdx.x * 4 + r;
    float acc = b[j];
#pragma unroll
    for (int k = 0; k < F_IN; ++k)
        acc = fmaf(xs[r * F_IN + k], Ws[k * HD + j], acc);
    float other = __shfl_xor(acc, 1);
    if (node < N_NODES && (j & 1) == 0)
        hb[node * 32 + (j >> 1)] = pack2(acc, other);
}

// ---------------- MFMA GEMM: two fp8 column-planes out ----------------
__global__ void __launch_bounds__(256)
k_gemm_mfma(const unsigned* __restrict__ Ab, const float* __restrict__ W,
            const float* __restrict__ coef, const float* __restrict__ dinv,
            unsigned* __restrict__ Cf8) {
    __shared__ short Wt[64 * 72];
    __shared__ float Cs[4][16 * 66];
    int t = threadIdx.x;

    for (int i = t; i < HD * HD; i += 256) {
        int k = i >> 6, j = i & 63;
        Wt[j * 72 + k] = (short)bf16r(W[i]);
    }
    __syncthreads();

    int wid = t >> 6, lane = t & 63;
    int rlane = lane & 15, kb = lane >> 4;
    int base = blockIdx.x * 64 + wid * 16;
    int arow = base + rlane;
    if (arow > N_NODES - 1) arow = N_NODES - 1;
    bool has_coef = (coef != nullptr);

    short8v afrag[2];
#pragma unroll
    for (int h = 0; h < 2; ++h) {
        uint4 p = *reinterpret_cast<const uint4*>(Ab + arow * 32 + h * 16 + kb * 4);
        union { uint4 u; short8v s; } cv;
        if (has_coef) {
            int k0 = h * 32 + kb * 8;
            float v0 = unlo(p.x), v1 = unhi(p.x), v2 = unlo(p.y), v3 = unhi(p.y);
            float v4 = unlo(p.z), v5 = unhi(p.z), v6 = unlo(p.w), v7 = unhi(p.w);
            v0 = fmaxf(fmaf(coef[k0 + 0], v0, coef[64 + k0 + 0]), 0.f);
            v1 = fmaxf(fmaf(coef[k0 + 1], v1, coef[64 + k0 + 1]), 0.f);
            v2 = fmaxf(fmaf(coef[k0 + 2], v2, coef[64 + k0 + 2]), 0.f);
            v3 = fmaxf(fmaf(coef[k0 + 3], v3, coef[64 + k0 + 3]), 0.f);
            v4 = fmaxf(fmaf(coef[k0 + 4], v4, coef[64 + k0 + 4]), 0.f);
            v5 = fmaxf(fmaf(coef[k0 + 5], v5, coef[64 + k0 + 5]), 0.f);
            v6 = fmaxf(fmaf(coef[k0 + 6], v6, coef[64 + k0 + 6]), 0.f);
            v7 = fmaxf(fmaf(coef[k0 + 7], v7, coef[64 + k0 + 7]), 0.f);
            cv.u.x = pack2(v0, v1); cv.u.y = pack2(v2, v3);
            cv.u.z = pack2(v4, v5); cv.u.w = pack2(v6, v7);
        } else {
            cv.u = p;
        }
        afrag[h] = cv.s;
    }

    f32x4 acc[4];
#pragma unroll
    for (int nt = 0; nt < 4; ++nt) acc[nt] = (f32x4){0.f, 0.f, 0.f, 0.f};

#pragma unroll
    for (int nt = 0; nt < 4; ++nt) {
        int col = nt * 16 + rlane;
#pragma unroll
        for (int h = 0; h < 2; ++h) {
            short8v b = *reinterpret_cast<const short8v*>(&Wt[col * 72 + h * 32 + kb * 8]);
            acc[nt] = __builtin_amdgcn_mfma_f32_16x16x32_bf16(afrag[h], b, acc[nt], 0, 0, 0);
        }
    }

    float dv[4];
#pragma unroll
    for (int r = 0; r < 4; ++r) {
        int g = base + kb * 4 + r;
        dv[r] = dinv[g > N_NODES - 1 ? N_NODES - 1 : g];
    }
#pragma unroll
    for (int nt = 0; nt < 4; ++nt) {
        int col = nt * 16 + rlane;
#pragma unroll
        for (int r = 0; r < 4; ++r)
            Cs[wid][(kb * 4 + r) * 66 + col] = acc[nt][r] * dv[r];
    }
    __syncthreads();

#pragma unroll
    for (int u = 0; u < 4; ++u) {
        int o = u * 64 + lane;
        int row = o >> 4, q = o & 15;
        int node = blockIdx.x * 64 + wid * 16 + row;
        if (node < N_NODES) {
            const float* cp = &Cs[wid][row * 66 + q * 4];
            unsigned val = pack_fp8x4(cp[0], cp[1], cp[2], cp[3]);
            if (q < 8) Cf8[node * 8 + q] = val;                  // plane 0 (cols 0-31)
            else       Cf8[NPLANE + node * 8 + (q - 8)] = val;   // plane 1 (cols 32-63)
        }
    }
}

// ---------------- CSR gather over ONE 3.2MB column-plane + half BN stats ----------------
// 8 threads/node (q=t&7), 32 groups, 4 serial nodes -> 128 nodes/block.
__global__ void __launch_bounds__(256)
k_gather_stats(const unsigned* __restrict__ plane, const int* __restrict__ row_start,
               const int* __restrict__ csr_src, const float* __restrict__ dinv,
               const float* __restrict__ cb /* offset by half */,
               uint2* __restrict__ hb2, float* __restrict__ stats_sh, int qoff) {
    int t = threadIdx.x;
    int q = t & 7;
    int r = t >> 3;
    float cb0 = cb[q * 4 + 0], cb1 = cb[q * 4 + 1];
    float cb2 = cb[q * 4 + 2], cb3 = cb[q * 4 + 3];
    float4 st_s = {0.f, 0.f, 0.f, 0.f}, st_q = {0.f, 0.f, 0.f, 0.f};

#pragma unroll
    for (int i = 0; i < 4; ++i) {
        int n = blockIdx.x * 128 + r * 4 + i;
        bool valid = (n < N_NODES);
        int beg = 0, end = 0;
        if (valid) { beg = row_start[n]; end = row_start[n + 1]; }
        float4 a0 = {0.f,0.f,0.f,0.f}, a1 = {0.f,0.f,0.f,0.f};
        float4 a2 = {0.f,0.f,0.f,0.f}, a3 = {0.f,0.f,0.f,0.f};
        if (valid) {
            unsigned p = plane[n * 8 + q];
            f32x2 lo = __builtin_amdgcn_cvt_pk_f32_fp8((int)p, false);
            f32x2 hi = __builtin_amdgcn_cvt_pk_f32_fp8((int)p, true);
            a0.x = lo[0]; a0.y = lo[1]; a0.z = hi[0]; a0.w = hi[1];
        }
        int e = beg;
        for (; e + 3 < end; e += 4) {
            int s0 = csr_src[e],     s1 = csr_src[e + 1];
            int s2 = csr_src[e + 2], s3 = csr_src[e + 3];
            unsigned p0 = plane[s0 * 8 + q], p1 = plane[s1 * 8 + q];
            unsigned p2 = plane[s2 * 8 + q], p3 = plane[s3 * 8 + q];
            f32x2 l0 = __builtin_amdgcn_cvt_pk_f32_fp8((int)p0, false);
            f32x2 h0 = __builtin_amdgcn_cvt_pk_f32_fp8((int)p0, true);
            f32x2 l1 = __builtin_amdgcn_cvt_pk_f32_fp8((int)p1, false);
            f32x2 h1 = __builtin_amdgcn_cvt_pk_f32_fp8((int)p1, true);
            f32x2 l2 = __builtin_amdgcn_cvt_pk_f32_fp8((int)p2, false);
            f32x2 h2 = __builtin_amdgcn_cvt_pk_f32_fp8((int)p2, true);
            f32x2 l3 = __builtin_amdgcn_cvt_pk_f32_fp8((int)p3, false);
            f32x2 h3 = __builtin_amdgcn_cvt_pk_f32_fp8((int)p3, true);
            a0.x += l0[0]; a0.y += l0[1]; a0.z += h0[0]; a0.w += h0[1];
            a1.x += l1[0]; a1.y += l1[1]; a1.z += h1[0]; a1.w += h1[1];
            a2.x += l2[0]; a2.y += l2[1]; a2.z += h2[0]; a2.w += h2[1];
            a3.x += l3[0]; a3.y += l3[1]; a3.z += h3[0]; a3.w += h3[1];
        }
        for (; e < end; ++e) {
            int s0 = csr_src[e];
            unsigned p0 = plane[s0 * 8 + q];
            f32x2 l0 = __builtin_amdgcn_cvt_pk_f32_fp8((int)p0, false);
            f32x2 h0 = __builtin_amdgcn_cvt_pk_f32_fp8((int)p0, true);
            a0.x += l0[0]; a0.y += l0[1]; a0.z += h0[0]; a0.w += h0[1];
        }
        float dn = valid ? dinv[n] : 0.f;
        float4 h;
        h.x = fmaf(a0.x + a1.x + a2.x + a3.x, dn, cb0);
        h.y = fmaf(a0.y + a1.y + a2.y + a3.y, dn, cb1);
        h.z = fmaf(a0.z + a1.z + a2.z + a3.z, dn, cb2);
        h.w = fmaf(a0.w + a1.w + a2.w + a3.w, dn, cb3);
        if (valid) {
            uint2 o;
            o.x = pack2(h.x, h.y);
            o.y = pack2(h.z, h.w);
            hb2[n * 16 + qoff + q] = o;
            st_s.x += h.x; st_s.y += h.y; st_s.z += h.z; st_s.w += h.w;
            st_q.x = fmaf(h.x, h.x, st_q.x); st_q.y = fmaf(h.y, h.y, st_q.y);
            st_q.z = fmaf(h.z, h.z, st_q.z); st_q.w = fmaf(h.w, h.w, st_q.w);
        }
    }

    __shared__ float4 ls_s[256], ls_q[256];
    ls_s[t] = st_s; ls_q[t] = st_q;
    __syncthreads();
    if (t < 8) {
        float4 ss = ls_s[t], qq = ls_q[t];
        for (int rr = 1; rr < 32; ++rr) {
            float4 u = ls_s[rr * 8 + t], v = ls_q[rr * 8 + t];
            ss.x += u.x; ss.y += u.y; ss.z += u.z; ss.w += u.w;
            qq.x += v.x; qq.y += v.y; qq.z += v.z; qq.w += v.w;
        }
        float* sh = stats_sh + (blockIdx.x & (NSHADOW - 1)) * 128;
        int j0 = qoff * 4 + 4 * t;
        atomicAdd(&sh[j0 + 0], ss.x);
        atomicAdd(&sh[j0 + 1], ss.y);
        atomicAdd(&sh[j0 + 2], ss.z);
        atomicAdd(&sh[j0 + 3], ss.w);
        atomicAdd(&sh[64 + j0 + 0], qq.x);
        atomicAdd(&sh[64 + j0 + 1], qq.y);
        atomicAdd(&sh[64 + j0 + 2], qq.z);
        atomicAdd(&sh[64 + j0 + 3], qq.w);
    }
}

// ---------------- shadow stats -> affine coef ----------------
__global__ void k_bn_coef(const float* __restrict__ stats_sh, const float* __restrict__ gamma,
                          const float* __restrict__ beta, float* __restrict__ coef) {
    int j = threadIdx.x;
    float s = 0.f, s2 = 0.f;
    for (int c = 0; c < NSHADOW; ++c) {
        s  += stats_sh[c * 128 + j];
        s2 += stats_sh[c * 128 + 64 + j];
    }
    float mu  = s * (1.0f / N_NODES);
    float var = s2 * (1.0f / N_NODES) - mu * mu;
    float rs  = rsqrtf(var + EPS);
    float a   = gamma[j] * rs;
    coef[j]      = a;
    coef[64 + j] = fmaf(-a, mu, beta[j]);
}

// ---------------- mean pool with fused BN+ReLU (bf16 h in) ----------------
__global__ void k_pool(const unsigned* __restrict__ hb, const float* __restrict__ coef,
                       float* __restrict__ pooled) {
    int t = threadIdx.x;
    int j = t & 63, rg = t >> 6;
    float a = coef[j], c = coef[64 + j];
    float s = 0.f;
    for (int n = blockIdx.x * 4 + rg; n < N_NODES; n += gridDim.x * 4) {
        unsigned p = hb[n * 32 + (j >> 1)];
        float v = (j & 1) ? unhi(p) : unlo(p);
        s += fmaxf(fmaf(a, v, c), 0.f);
    }
    __shared__ float ls[256];
    ls[t] = s;
    __syncthreads();
    if (t < 64)
        atomicAdd(&pooled[j], ls[t] + ls[t + 64] + ls[t + 128] + ls[t + 192]);
}

// ---------------- output ----------------
__global__ void k_out(const float* __restrict__ pooled, const float* __restrict__ Wout,
                      const float* __restrict__ bout, float* __restrict__ out) {
    int o = threadIdx.x;
    float acc = bout[o];
#pragma unroll
    for (int k = 0; k < HD; ++k)
        acc = fmaf(pooled[k] * (1.0f / N_NODES), Wout[k * HD + o], acc);
    out[o] = acc;
}

extern "C" void kernel_launch(void* const* d_in, const int* in_sizes, int n_in,
                              void* d_out, int out_size, void* d_ws, size_t ws_size,
                              hipStream_t stream) {
    const float* x        = (const float*)d_in[0];
    const int*   ei       = (const int*)  d_in[1];
    const float* W_embed  = (const float*)d_in[2];
    const float* b_embed  = (const float*)d_in[3];
    const float* conv_W   = (const float*)d_in[4];
    const float* conv_b   = (const float*)d_in[5];
    const float* bn_gamma = (const float*)d_in[6];
    const float* bn_beta  = (const float*)d_in[7];
    const float* W_out    = (const float*)d_in[8];
    const float* b_out    = (const float*)d_in[9];
    float* out = (float*)d_out;

    float* ws = (float*)d_ws;
    float* dinv      = ws;                                // N
    int*   row_start = (int*)(ws + N_NODES);              // N+1 (pad 8)
    float* small     = ws + 2 * N_NODES + 8;
    float* stats_sh  = small;                             // 4 layers * NSHADOW*128 = 32768
    float* pooled    = small + 32768;                     // 64
    float* coef      = small + 32832;                     // 4*128 = 512
    int*   flag      = (int*)(small + 33344);             // 1 (pad 64)
    int*   csr_src   = (int*)(small + 33408);             // E
    int*   hcnt      = (int*)(small + 33408 + N_EDGES);   // NP*NB1 = 49000
    int*   off_bp    = hcnt + NP * NB1;                   // 49000
    int*   ptotal    = off_bp + NP * NB1;                 // 256
    int*   pbase     = ptotal + 256;                      // 256
    uint2* part_buf  = (uint2*)(pbase + 256);             // E uint2 (12.8 MB)
    float* bufA      = (float*)(part_buf + N_EDGES);      // N*32 uints (bf16 h)
    float* bufB      = bufA + N_NODES * 32;               // 2 planes * N*8 uints (fp8 xw)

    k_detect<<<1, 64, 0, stream>>>(ei, flag);
    k_p1_hist<<<NB1, 256, 0, stream>>>(ei, flag, hcnt);
    k_p2scan<<<NP, 256, 0, stream>>>(hcnt, off_bp, ptotal);
    k_p3scan<<<1, 256, 0, stream>>>(ptotal, pbase);
    k_p2_scatter<<<NB1, 256, 0, stream>>>(ei, flag, off_bp, pbase, part_buf);
    k_p3_build<<<NP, 256, 0, stream>>>(part_buf, pbase, ptotal, row_start, dinv, csr_src);
    k_embed<<<(N_NODES + 3) / 4, 256, 0, stream>>>(x, W_embed, b_embed, (unsigned*)bufA);
    hipMemsetAsync(stats_sh, 0, 4 * NSHADOW * 128 * sizeof(float), stream);

    for (int l = 0; l < 4; ++l) {
        float* st = stats_sh + l * NSHADOW * 128;
        k_gemm_mfma<<<(N_NODES + 63) / 64, 256, 0, stream>>>(
            (const unsigned*)bufA, conv_W + l * HD * HD,
            l ? coef + (l - 1) * 128 : nullptr, dinv, (unsigned*)bufB);
        k_gather_stats<<<(N_NODES + 127) / 128, 256, 0, stream>>>(
            (const unsigned*)bufB, row_start, csr_src, dinv,
            conv_b + l * HD, (uint2*)bufA, st, 0);
        k_gather_stats<<<(N_NODES + 127) / 128, 256, 0, stream>>>(
            (const unsigned*)bufB + NPLANE, row_start, csr_src, dinv,
            conv_b + l * HD + 32, (uint2*)bufA, st, 8);
        k_bn_coef<<<1, 64, 0, stream>>>(st, bn_gamma + l * HD, bn_beta + l * HD,
                                        coef + l * 128);
    }

    hipMemsetAsync(pooled, 0, 64 * sizeof(float), stream);
    k_pool<<<1024, 256, 0, stream>>>((const unsigned*)bufA, coef + 3 * 128, pooled);
    k_out<<<1, 64, 0, stream>>>(pooled, W_out, b_out, out);
}

// Round 19
// 336.993 us; speedup vs baseline: 1.2690x; 1.2690x over previous
//
#include <hip/hip_runtime.h>

#define N_NODES 100000
#define N_EDGES 1600000
#define F_IN    32
#define HD      64
#define EPS     1e-5f
#define NSHADOW 64
#define NP      196      // partitions (512 nodes each)
#define PWS     9        // partition width shift
#define NB1     250      // blocks in pass1/2
#define EPB     6400     // edges per block (250*6400 = E exactly)

typedef __attribute__((ext_vector_type(8))) short short8v;
typedef __attribute__((ext_vector_type(4))) float f32x4;
typedef __attribute__((ext_vector_type(2))) float f32x2;

__device__ __forceinline__ unsigned bf16r(float f) {
    unsigned u = __float_as_uint(f);
    return (u + 0x7fffu + ((u >> 16) & 1u)) >> 16;
}
__device__ __forceinline__ unsigned pack2(float lo, float hi) {
    return bf16r(lo) | (bf16r(hi) << 16);
}
__device__ __forceinline__ float unlo(unsigned u) { return __uint_as_float(u << 16); }
__device__ __forceinline__ float unhi(unsigned u) { return __uint_as_float(u & 0xffff0000u); }

__device__ __forceinline__ unsigned pack_fp8x4(float a, float b, float c, float d) {
    int v = __builtin_amdgcn_cvt_pk_fp8_f32(a, b, 0, false);
    v = __builtin_amdgcn_cvt_pk_fp8_f32(c, d, v, true);
    return (unsigned)v;
}

// ---------------- edge-index dtype probe ----------------
__global__ void k_detect(const int* __restrict__ ei, int* __restrict__ flag) {
    if (threadIdx.x == 0 && blockIdx.x == 0) {
        int all_zero = 1;
        for (int k = 0; k < 64; ++k)
            if (ei[2 * k + 1] != 0) { all_zero = 0; break; }
        *flag = all_zero;   // 1 -> int64 layout, 0 -> int32 layout
    }
}

__device__ __forceinline__ int load_src(const int* ei, int e, int is64) {
    return is64 ? ei[2 * e] : ei[e];
}
__device__ __forceinline__ int load_dst(const int* ei, int e, int is64) {
    return is64 ? ei[2 * (N_EDGES + e)] : ei[N_EDGES + e];
}

// ---------------- CSR build pass 1: per-(block,partition) histogram ----------------
__global__ void __launch_bounds__(256)
k_p1_hist(const int* __restrict__ ei, const int* __restrict__ flag, int* __restrict__ hcnt) {
    __shared__ int hist[NP];
    int t = threadIdx.x, b = blockIdx.x;
    if (t < NP) hist[t] = 0;
    __syncthreads();
    int is64 = *flag;
#pragma unroll 5
    for (int i = 0; i < 25; ++i) {
        int e = b * EPB + i * 256 + t;
        int d = load_dst(ei, e, is64);
        atomicAdd(&hist[d >> PWS], 1);
    }
    __syncthreads();
    if (t < NP) hcnt[t * NB1 + b] = hist[t];
}

// ---------------- per-partition exclusive scan over blocks ----------------
__global__ void k_p2scan(const int* __restrict__ hcnt, int* __restrict__ off_bp,
                         int* __restrict__ ptotal) {
    __shared__ int ls[256];
    int t = threadIdx.x, p = blockIdx.x;
    int v = (t < NB1) ? hcnt[p * NB1 + t] : 0;
    ls[t] = v;
    __syncthreads();
    for (int off = 1; off < 256; off <<= 1) {
        int u = (t >= off) ? ls[t - off] : 0;
        __syncthreads();
        ls[t] += u;
        __syncthreads();
    }
    if (t < NB1) off_bp[p * NB1 + t] = ls[t] - v;
    if (t == 255) ptotal[p] = ls[255];
}

// ---------------- scan partition totals -> pbase ----------------
__global__ void k_p3scan(const int* __restrict__ ptotal, int* __restrict__ pbase) {
    __shared__ int ls[256];
    int t = threadIdx.x;
    int v = (t < NP) ? ptotal[t] : 0;
    ls[t] = v;
    __syncthreads();
    for (int off = 1; off < 256; off <<= 1) {
        int u = (t >= off) ? ls[t - off] : 0;
        __syncthreads();
        ls[t] += u;
        __syncthreads();
    }
    if (t < NP) pbase[t] = ls[t] - v;
}

// ---------------- scatter edge records into partition buffer ----------------
__global__ void __launch_bounds__(256)
k_p2_scatter(const int* __restrict__ ei, const int* __restrict__ flag,
             const int* __restrict__ off_bp, const int* __restrict__ pbase,
             uint2* __restrict__ part_buf) {
    __shared__ int cursor[NP];
    int t = threadIdx.x, b = blockIdx.x;
    if (t < NP) cursor[t] = pbase[t] + off_bp[t * NB1 + b];
    __syncthreads();
    int is64 = *flag;
#pragma unroll 5
    for (int i = 0; i < 25; ++i) {
        int e = b * EPB + i * 256 + t;
        int s = load_src(ei, e, is64);
        int d = load_dst(ei, e, is64);
        int slot = atomicAdd(&cursor[d >> PWS], 1);
        part_buf[slot] = make_uint2((unsigned)s, (unsigned)d);
    }
}

// ---------------- fused pass 3: hist -> LDS scan -> row_start+dinv -> csr place ----------------
__global__ void __launch_bounds__(256)
k_p3_build(const uint2* __restrict__ part_buf, const int* __restrict__ pbase,
           const int* __restrict__ ptotal, int* __restrict__ row_start,
           float* __restrict__ dinv, int* __restrict__ csr_src) {
    __shared__ int hist[512];
    __shared__ int s2[256];
    __shared__ int cur[512];
    int t = threadIdx.x, p = blockIdx.x;
    hist[t] = 0; hist[t + 256] = 0;
    __syncthreads();
    int beg = pbase[p], cnt = ptotal[p];
    for (int r = t; r < cnt; r += 256)
        atomicAdd(&hist[part_buf[beg + r].y & 511], 1);
    __syncthreads();
    int d0 = hist[2 * t], d1 = hist[2 * t + 1];
    s2[t] = d0 + d1;
    __syncthreads();
    for (int off = 1; off < 256; off <<= 1) {
        int u = (t >= off) ? s2[t - off] : 0;
        __syncthreads();
        s2[t] += u;
        __syncthreads();
    }
    int ex = (t == 0) ? 0 : s2[t - 1];
    int rs0 = beg + ex, rs1 = beg + ex + d0;
    int n0 = (p << PWS) + 2 * t;
    if (n0 < N_NODES)     { row_start[n0]     = rs0; dinv[n0]     = rsqrtf((float)d0 + 1.f); }
    if (n0 + 1 < N_NODES) { row_start[n0 + 1] = rs1; dinv[n0 + 1] = rsqrtf((float)d1 + 1.f); }
    cur[2 * t] = rs0; cur[2 * t + 1] = rs1;
    if (p == NP - 1 && t == 0) row_start[N_NODES] = N_EDGES;
    __syncthreads();
    for (int r = t; r < cnt; r += 256) {
        uint2 rec = part_buf[beg + r];
        int slot = atomicAdd(&cur[rec.y & 511], 1);
        csr_src[slot] = (int)rec.x;
    }
}

// ---------------- node embedding: hb = bf16(x @ W_embed + b) ----------------
__global__ void k_embed(const float* __restrict__ x, const float* __restrict__ W,
                        const float* __restrict__ b, unsigned* __restrict__ hb) {
    __shared__ float Ws[F_IN * HD];
    __shared__ float xs[4 * F_IN];
    int t = threadIdx.x;
    for (int i = t; i < F_IN * HD; i += 256) Ws[i] = W[i];
    if (t < 4 * F_IN) {
        int r = t >> 5, c = t & 31;
        int node = blockIdx.x * 4 + r;
        xs[t] = (node < N_NODES) ? x[node * F_IN + c] : 0.f;
    }
    __syncthreads();
    int r = t >> 6, j = t & 63;
    int node = blockIdx.x * 4 + r;
    float acc = b[j];
#pragma unroll
    for (int k = 0; k < F_IN; ++k)
        acc = fmaf(xs[r * F_IN + k], Ws[k * HD + j], acc);
    float other = __shfl_xor(acc, 1);
    if (node < N_NODES && (j & 1) == 0)
        hb[node * 32 + (j >> 1)] = pack2(acc, other);
}

// ---------------- MFMA GEMM: Cf8[n] = fp8((relu(a*hb[n]+c) @ W) * dinv[n]) ----------------
__global__ void __launch_bounds__(256)
k_gemm_mfma(const unsigned* __restrict__ Ab, const float* __restrict__ W,
            const float* __restrict__ coef, const float* __restrict__ dinv,
            unsigned* __restrict__ Cf8) {
    __shared__ short Wt[64 * 72];
    __shared__ float Cs[4][16 * 66];
    int t = threadIdx.x;

    for (int i = t; i < HD * HD; i += 256) {
        int k = i >> 6, j = i & 63;
        Wt[j * 72 + k] = (short)bf16r(W[i]);
    }
    __syncthreads();

    int wid = t >> 6, lane = t & 63;
    int rlane = lane & 15, kb = lane >> 4;
    int base = blockIdx.x * 64 + wid * 16;
    int arow = base + rlane;
    if (arow > N_NODES - 1) arow = N_NODES - 1;
    bool has_coef = (coef != nullptr);

    short8v afrag[2];
#pragma unroll
    for (int h = 0; h < 2; ++h) {
        uint4 p = *reinterpret_cast<const uint4*>(Ab + arow * 32 + h * 16 + kb * 4);
        union { uint4 u; short8v s; } cv;
        if (has_coef) {
            int k0 = h * 32 + kb * 8;
            float v0 = unlo(p.x), v1 = unhi(p.x), v2 = unlo(p.y), v3 = unhi(p.y);
            float v4 = unlo(p.z), v5 = unhi(p.z), v6 = unlo(p.w), v7 = unhi(p.w);
            v0 = fmaxf(fmaf(coef[k0 + 0], v0, coef[64 + k0 + 0]), 0.f);
            v1 = fmaxf(fmaf(coef[k0 + 1], v1, coef[64 + k0 + 1]), 0.f);
            v2 = fmaxf(fmaf(coef[k0 + 2], v2, coef[64 + k0 + 2]), 0.f);
            v3 = fmaxf(fmaf(coef[k0 + 3], v3, coef[64 + k0 + 3]), 0.f);
            v4 = fmaxf(fmaf(coef[k0 + 4], v4, coef[64 + k0 + 4]), 0.f);
            v5 = fmaxf(fmaf(coef[k0 + 5], v5, coef[64 + k0 + 5]), 0.f);
            v6 = fmaxf(fmaf(coef[k0 + 6], v6, coef[64 + k0 + 6]), 0.f);
            v7 = fmaxf(fmaf(coef[k0 + 7], v7, coef[64 + k0 + 7]), 0.f);
            cv.u.x = pack2(v0, v1); cv.u.y = pack2(v2, v3);
            cv.u.z = pack2(v4, v5); cv.u.w = pack2(v6, v7);
        } else {
            cv.u = p;
        }
        afrag[h] = cv.s;
    }

    f32x4 acc[4];
#pragma unroll
    for (int nt = 0; nt < 4; ++nt) acc[nt] = (f32x4){0.f, 0.f, 0.f, 0.f};

#pragma unroll
    for (int nt = 0; nt < 4; ++nt) {
        int col = nt * 16 + rlane;
#pragma unroll
        for (int h = 0; h < 2; ++h) {
            short8v b = *reinterpret_cast<const short8v*>(&Wt[col * 72 + h * 32 + kb * 8]);
            acc[nt] = __builtin_amdgcn_mfma_f32_16x16x32_bf16(afrag[h], b, acc[nt], 0, 0, 0);
        }
    }

    float dv[4];
#pragma unroll
    for (int r = 0; r < 4; ++r) {
        int g = base + kb * 4 + r;
        dv[r] = dinv[g > N_NODES - 1 ? N_NODES - 1 : g];
    }
#pragma unroll
    for (int nt = 0; nt < 4; ++nt) {
        int col = nt * 16 + rlane;
#pragma unroll
        for (int r = 0; r < 4; ++r)
            Cs[wid][(kb * 4 + r) * 66 + col] = acc[nt][r] * dv[r];
    }
    __syncthreads();

#pragma unroll
    for (int u = 0; u < 4; ++u) {
        int o = u * 64 + lane;
        int row = o >> 4, q = o & 15;
        int node = blockIdx.x * 64 + wid * 16 + row;
        if (node < N_NODES) {
            const float* cp = &Cs[wid][row * 66 + q * 4];
            Cf8[node * 16 + q] = pack_fp8x4(cp[0], cp[1], cp[2], cp[3]);
        }
    }
}

// ---------------- CSR gather (fp8 messages, 64B rows) + fused BN stats ----------------
// 64 nodes/block; 16-thread group handles 4 nodes serially; 4-deep edge unroll.
__global__ void __launch_bounds__(256)
k_gather_stats(const unsigned* __restrict__ xwf8, const int* __restrict__ row_start,
               const int* __restrict__ csr_src, const float* __restrict__ dinv,
               const float* __restrict__ cb, uint2* __restrict__ hb2,
               float* __restrict__ stats_sh) {
    int t = threadIdx.x;
    int q = t & 15;
    int r = t >> 4;
    float cb0 = cb[q * 4 + 0], cb1 = cb[q * 4 + 1];
    float cb2 = cb[q * 4 + 2], cb3 = cb[q * 4 + 3];
    float4 st_s = {0.f, 0.f, 0.f, 0.f}, st_q = {0.f, 0.f, 0.f, 0.f};

#pragma unroll
    for (int i = 0; i < 4; ++i) {
        int n = blockIdx.x * 64 + r * 4 + i;
        bool valid = (n < N_NODES);
        int beg = 0, end = 0;
        if (valid) { beg = row_start[n]; end = row_start[n + 1]; }
        float4 a0 = {0.f,0.f,0.f,0.f}, a1 = {0.f,0.f,0.f,0.f};
        float4 a2 = {0.f,0.f,0.f,0.f}, a3 = {0.f,0.f,0.f,0.f};
        if (valid) {
            unsigned p = xwf8[n * 16 + q];
            f32x2 lo = __builtin_amdgcn_cvt_pk_f32_fp8((int)p, false);
            f32x2 hi = __builtin_amdgcn_cvt_pk_f32_fp8((int)p, true);
            a0.x = lo[0]; a0.y = lo[1]; a0.z = hi[0]; a0.w = hi[1];
        }
        int e = beg;
        for (; e + 3 < end; e += 4) {
            int s0 = csr_src[e],     s1 = csr_src[e + 1];
            int s2 = csr_src[e + 2], s3 = csr_src[e + 3];
            unsigned p0 = xwf8[s0 * 16 + q], p1 = xwf8[s1 * 16 + q];
            unsigned p2 = xwf8[s2 * 16 + q], p3 = xwf8[s3 * 16 + q];
            f32x2 l0 = __builtin_amdgcn_cvt_pk_f32_fp8((int)p0, false);
            f32x2 h0 = __builtin_amdgcn_cvt_pk_f32_fp8((int)p0, true);
            f32x2 l1 = __builtin_amdgcn_cvt_pk_f32_fp8((int)p1, false);
            f32x2 h1 = __builtin_amdgcn_cvt_pk_f32_fp8((int)p1, true);
            f32x2 l2 = __builtin_amdgcn_cvt_pk_f32_fp8((int)p2, false);
            f32x2 h2 = __builtin_amdgcn_cvt_pk_f32_fp8((int)p2, true);
            f32x2 l3 = __builtin_amdgcn_cvt_pk_f32_fp8((int)p3, false);
            f32x2 h3 = __builtin_amdgcn_cvt_pk_f32_fp8((int)p3, true);
            a0.x += l0[0]; a0.y += l0[1]; a0.z += h0[0]; a0.w += h0[1];
            a1.x += l1[0]; a1.y += l1[1]; a1.z += h1[0]; a1.w += h1[1];
            a2.x += l2[0]; a2.y += l2[1]; a2.z += h2[0]; a2.w += h2[1];
            a3.x += l3[0]; a3.y += l3[1]; a3.z += h3[0]; a3.w += h3[1];
        }
        for (; e < end; ++e) {
            int s0 = csr_src[e];
            unsigned p0 = xwf8[s0 * 16 + q];
            f32x2 l0 = __builtin_amdgcn_cvt_pk_f32_fp8((int)p0, false);
            f32x2 h0 = __builtin_amdgcn_cvt_pk_f32_fp8((int)p0, true);
            a0.x += l0[0]; a0.y += l0[1]; a0.z += h0[0]; a0.w += h0[1];
        }
        float dn = valid ? dinv[n] : 0.f;
        float4 h;
        h.x = fmaf(a0.x + a1.x + a2.x + a3.x, dn, cb0);
        h.y = fmaf(a0.y + a1.y + a2.y + a3.y, dn, cb1);
        h.z = fmaf(a0.z + a1.z + a2.z + a3.z, dn, cb2);
        h.w = fmaf(a0.w + a1.w + a2.w + a3.w, dn, cb3);
        if (valid) {
            uint2 o;
            o.x = pack2(h.x, h.y);
            o.y = pack2(h.z, h.w);
            hb2[n * 16 + q] = o;
            st_s.x += h.x; st_s.y += h.y; st_s.z += h.z; st_s.w += h.w;
            st_q.x = fmaf(h.x, h.x, st_q.x); st_q.y = fmaf(h.y, h.y, st_q.y);
            st_q.z = fmaf(h.z, h.z, st_q.z); st_q.w = fmaf(h.w, h.w, st_q.w);
        }
    }

    __shared__ float4 ls_s[256], ls_q[256];
    ls_s[t] = st_s; ls_q[t] = st_q;
    __syncthreads();
    if (t < 16) {
        float4 ss = ls_s[t], qq = ls_q[t];
        for (int rr = 1; rr < 16; ++rr) {
            float4 u = ls_s[rr * 16 + t], v = ls_q[rr * 16 + t];
            ss.x += u.x; ss.y += u.y; ss.z += u.z; ss.w += u.w;
            qq.x += v.x; qq.y += v.y; qq.z += v.z; qq.w += v.w;
        }
        float* sh = stats_sh + (blockIdx.x & (NSHADOW - 1)) * 128;
        atomicAdd(&sh[4 * t + 0], ss.x);
        atomicAdd(&sh[4 * t + 1], ss.y);
        atomicAdd(&sh[4 * t + 2], ss.z);
        atomicAdd(&sh[4 * t + 3], ss.w);
        atomicAdd(&sh[64 + 4 * t + 0], qq.x);
        atomicAdd(&sh[64 + 4 * t + 1], qq.y);
        atomicAdd(&sh[64 + 4 * t + 2], qq.z);
        atomicAdd(&sh[64 + 4 * t + 3], qq.w);
    }
}

// ---------------- shadow stats -> affine coef ----------------
__global__ void k_bn_coef(const float* __restrict__ stats_sh, const float* __restrict__ gamma,
                          const float* __restrict__ beta, float* __restrict__ coef) {
    int j = threadIdx.x;
    float s = 0.f, s2 = 0.f;
    for (int c = 0; c < NSHADOW; ++c) {
        s  += stats_sh[c * 128 + j];
        s2 += stats_sh[c * 128 + 64 + j];
    }
    float mu  = s * (1.0f / N_NODES);
    float var = s2 * (1.0f / N_NODES) - mu * mu;
    float rs  = rsqrtf(var + EPS);
    float a   = gamma[j] * rs;
    coef[j]      = a;
    coef[64 + j] = fmaf(-a, mu, beta[j]);
}

// ---------------- mean pool with fused BN+ReLU (bf16 h in) ----------------
__global__ void k_pool(const unsigned* __restrict__ hb, const float* __restrict__ coef,
                       float* __restrict__ pooled) {
    int t = threadIdx.x;
    int j = t & 63, rg = t >> 6;
    float a = coef[j], c = coef[64 + j];
    float s = 0.f;
    for (int n = blockIdx.x * 4 + rg; n < N_NODES; n += gridDim.x * 4) {
        unsigned p = hb[n * 32 + (j >> 1)];
        float v = (j & 1) ? unhi(p) : unlo(p);
        s += fmaxf(fmaf(a, v, c), 0.f);
    }
    __shared__ float ls[256];
    ls[t] = s;
    __syncthreads();
    if (t < 64)
        atomicAdd(&pooled[j], ls[t] + ls[t + 64] + ls[t + 128] + ls[t + 192]);
}

// ---------------- output ----------------
__global__ void k_out(const float* __restrict__ pooled, const float* __restrict__ Wout,
                      const float* __restrict__ bout, float* __restrict__ out) {
    int o = threadIdx.x;
    float acc = bout[o];
#pragma unroll
    for (int k = 0; k < HD; ++k)
        acc = fmaf(pooled[k] * (1.0f / N_NODES), Wout[k * HD + o], acc);
    out[o] = acc;
}

extern "C" void kernel_launch(void* const* d_in, const int* in_sizes, int n_in,
                              void* d_out, int out_size, void* d_ws, size_t ws_size,
                              hipStream_t stream) {
    const float* x        = (const float*)d_in[0];
    const int*   ei       = (const int*)  d_in[1];
    const float* W_embed  = (const float*)d_in[2];
    const float* b_embed  = (const float*)d_in[3];
    const float* conv_W   = (const float*)d_in[4];
    const float* conv_b   = (const float*)d_in[5];
    const float* bn_gamma = (const float*)d_in[6];
    const float* bn_beta  = (const float*)d_in[7];
    const float* W_out    = (const float*)d_in[8];
    const float* b_out    = (const float*)d_in[9];
    float* out = (float*)d_out;

    float* ws = (float*)d_ws;
    float* dinv      = ws;                                // N
    int*   row_start = (int*)(ws + N_NODES);              // N+1 (pad 8)
    float* small     = ws + 2 * N_NODES + 8;
    float* stats_sh  = small;                             // 4 layers * NSHADOW*128 = 32768
    float* pooled    = small + 32768;                     // 64
    float* coef      = small + 32832;                     // 4*128 = 512
    int*   flag      = (int*)(small + 33344);             // 1 (pad 64)
    int*   csr_src   = (int*)(small + 33408);             // E
    int*   hcnt      = (int*)(small + 33408 + N_EDGES);   // NP*NB1 = 49000
    int*   off_bp    = hcnt + NP * NB1;                   // 49000
    int*   ptotal    = off_bp + NP * NB1;                 // 256
    int*   pbase     = ptotal + 256;                      // 256
    uint2* part_buf  = (uint2*)(pbase + 256);             // E uint2 (12.8 MB)
    float* bufA      = (float*)(part_buf + N_EDGES);      // N*32 uints (bf16 h)
    float* bufB      = bufA + N_NODES * 32;               // N*16 uints (fp8 xw)

    k_detect<<<1, 64, 0, stream>>>(ei, flag);
    k_p1_hist<<<NB1, 256, 0, stream>>>(ei, flag, hcnt);
    k_p2scan<<<NP, 256, 0, stream>>>(hcnt, off_bp, ptotal);
    k_p3scan<<<1, 256, 0, stream>>>(ptotal, pbase);
    k_p2_scatter<<<NB1, 256, 0, stream>>>(ei, flag, off_bp, pbase, part_buf);
    k_p3_build<<<NP, 256, 0, stream>>>(part_buf, pbase, ptotal, row_start, dinv, csr_src);
    k_embed<<<(N_NODES + 3) / 4, 256, 0, stream>>>(x, W_embed, b_embed, (unsigned*)bufA);
    hipMemsetAsync(stats_sh, 0, 4 * NSHADOW * 128 * sizeof(float), stream);

    for (int l = 0; l < 4; ++l) {
        float* st = stats_sh + l * NSHADOW * 128;
        k_gemm_mfma<<<(N_NODES + 63) / 64, 256, 0, stream>>>(
            (const unsigned*)bufA, conv_W + l * HD * HD,
            l ? coef + (l - 1) * 128 : nullptr, dinv, (unsigned*)bufB);
        k_gather_stats<<<(N_NODES + 63) / 64, 256, 0, stream>>>(
            (const unsigned*)bufB, row_start, csr_src, dinv, conv_b + l * HD,
            (uint2*)bufA, st);
        k_bn_coef<<<1, 64, 0, stream>>>(st, bn_gamma + l * HD, bn_beta + l * HD,
                                        coef + l * 128);
    }

    hipMemsetAsync(pooled, 0, 64 * sizeof(float), stream);
    k_pool<<<1024, 256, 0, stream>>>((const unsigned*)bufA, coef + 3 * 128, pooled);
    k_out<<<1, 64, 0, stream>>>(pooled, W_out, b_out, out);
}

// Round 20
// 311.397 us; speedup vs baseline: 1.3734x; 1.0822x over previous
//
#include <hip/hip_runtime.h>

#define N_NODES 100000
#define N_EDGES 1600000
#define F_IN    32
#define HD      64
#define EPS     1e-5f
#define NSHADOW 64
#define NP      196      // partitions (512 nodes each)
#define PWS     9        // partition width shift
#define NB1     250      // blocks in pass1/2
#define EPB     6400     // edges per block (250*6400 = E exactly)

typedef __attribute__((ext_vector_type(8))) short short8v;
typedef __attribute__((ext_vector_type(4))) float f32x4;
typedef __attribute__((ext_vector_type(2))) float f32x2;

__device__ __forceinline__ unsigned bf16r(float f) {
    unsigned u = __float_as_uint(f);
    return (u + 0x7fffu + ((u >> 16) & 1u)) >> 16;
}
__device__ __forceinline__ unsigned pack2(float lo, float hi) {
    return bf16r(lo) | (bf16r(hi) << 16);
}
__device__ __forceinline__ float unlo(unsigned u) { return __uint_as_float(u << 16); }
__device__ __forceinline__ float unhi(unsigned u) { return __uint_as_float(u & 0xffff0000u); }

__device__ __forceinline__ unsigned pack_fp8x4(float a, float b, float c, float d) {
    int v = __builtin_amdgcn_cvt_pk_fp8_f32(a, b, 0, false);
    v = __builtin_amdgcn_cvt_pk_fp8_f32(c, d, v, true);
    return (unsigned)v;
}
#define DECODE8(p, A) do { \
    f32x2 _lo = __builtin_amdgcn_cvt_pk_f32_fp8((int)(p), false); \
    f32x2 _hi = __builtin_amdgcn_cvt_pk_f32_fp8((int)(p), true);  \
    (A).x += _lo[0]; (A).y += _lo[1]; (A).z += _hi[0]; (A).w += _hi[1]; \
} while (0)

// ---------------- edge-index dtype probe ----------------
__global__ void k_detect(const int* __restrict__ ei, int* __restrict__ flag) {
    if (threadIdx.x == 0 && blockIdx.x == 0) {
        int all_zero = 1;
        for (int k = 0; k < 64; ++k)
            if (ei[2 * k + 1] != 0) { all_zero = 0; break; }
        *flag = all_zero;   // 1 -> int64 layout, 0 -> int32 layout
    }
}

__device__ __forceinline__ int load_src(const int* ei, int e, int is64) {
    return is64 ? ei[2 * e] : ei[e];
}
__device__ __forceinline__ int load_dst(const int* ei, int e, int is64) {
    return is64 ? ei[2 * (N_EDGES + e)] : ei[N_EDGES + e];
}

// ---------------- CSR build pass 1: per-(block,partition) histogram ----------------
__global__ void __launch_bounds__(256)
k_p1_hist(const int* __restrict__ ei, const int* __restrict__ flag, int* __restrict__ hcnt) {
    __shared__ int hist[NP];
    int t = threadIdx.x, b = blockIdx.x;
    if (t < NP) hist[t] = 0;
    __syncthreads();
    int is64 = *flag;
#pragma unroll 5
    for (int i = 0; i < 25; ++i) {
        int e = b * EPB + i * 256 + t;
        int d = load_dst(ei, e, is64);
        atomicAdd(&hist[d >> PWS], 1);
    }
    __syncthreads();
    if (t < NP) hcnt[t * NB1 + b] = hist[t];
}

// ---------------- per-partition exclusive scan over blocks ----------------
__global__ void k_p2scan(const int* __restrict__ hcnt, int* __restrict__ off_bp,
                         int* __restrict__ ptotal) {
    __shared__ int ls[256];
    int t = threadIdx.x, p = blockIdx.x;
    int v = (t < NB1) ? hcnt[p * NB1 + t] : 0;
    ls[t] = v;
    __syncthreads();
    for (int off = 1; off < 256; off <<= 1) {
        int u = (t >= off) ? ls[t - off] : 0;
        __syncthreads();
        ls[t] += u;
        __syncthreads();
    }
    if (t < NB1) off_bp[p * NB1 + t] = ls[t] - v;
    if (t == 255) ptotal[p] = ls[255];
}

// ---------------- scan partition totals -> pbase ----------------
__global__ void k_p3scan(const int* __restrict__ ptotal, int* __restrict__ pbase) {
    __shared__ int ls[256];
    int t = threadIdx.x;
    int v = (t < NP) ? ptotal[t] : 0;
    ls[t] = v;
    __syncthreads();
    for (int off = 1; off < 256; off <<= 1) {
        int u = (t >= off) ? ls[t - off] : 0;
        __syncthreads();
        ls[t] += u;
        __syncthreads();
    }
    if (t < NP) pbase[t] = ls[t] - v;
}

// ---------------- scatter edge records into partition buffer ----------------
__global__ void __launch_bounds__(256)
k_p2_scatter(const int* __restrict__ ei, const int* __restrict__ flag,
             const int* __restrict__ off_bp, const int* __restrict__ pbase,
             uint2* __restrict__ part_buf) {
    __shared__ int cursor[NP];
    int t = threadIdx.x, b = blockIdx.x;
    if (t < NP) cursor[t] = pbase[t] + off_bp[t * NB1 + b];
    __syncthreads();
    int is64 = *flag;
#pragma unroll 5
    for (int i = 0; i < 25; ++i) {
        int e = b * EPB + i * 256 + t;
        int s = load_src(ei, e, is64);
        int d = load_dst(ei, e, is64);
        int slot = atomicAdd(&cursor[d >> PWS], 1);
        part_buf[slot] = make_uint2((unsigned)s, (unsigned)d);
    }
}

// ---------------- fused pass 3: hist -> LDS scan -> row_start+dinv -> csr place ----------------
__global__ void __launch_bounds__(256)
k_p3_build(const uint2* __restrict__ part_buf, const int* __restrict__ pbase,
           const int* __restrict__ ptotal, int* __restrict__ row_start,
           float* __restrict__ dinv, int* __restrict__ csr_src) {
    __shared__ int hist[512];
    __shared__ int s2[256];
    __shared__ int cur[512];
    int t = threadIdx.x, p = blockIdx.x;
    hist[t] = 0; hist[t + 256] = 0;
    __syncthreads();
    int beg = pbase[p], cnt = ptotal[p];
    for (int r = t; r < cnt; r += 256)
        atomicAdd(&hist[part_buf[beg + r].y & 511], 1);
    __syncthreads();
    int d0 = hist[2 * t], d1 = hist[2 * t + 1];
    s2[t] = d0 + d1;
    __syncthreads();
    for (int off = 1; off < 256; off <<= 1) {
        int u = (t >= off) ? s2[t - off] : 0;
        __syncthreads();
        s2[t] += u;
        __syncthreads();
    }
    int ex = (t == 0) ? 0 : s2[t - 1];
    int rs0 = beg + ex, rs1 = beg + ex + d0;
    int n0 = (p << PWS) + 2 * t;
    if (n0 < N_NODES)     { row_start[n0]     = rs0; dinv[n0]     = rsqrtf((float)d0 + 1.f); }
    if (n0 + 1 < N_NODES) { row_start[n0 + 1] = rs1; dinv[n0 + 1] = rsqrtf((float)d1 + 1.f); }
    cur[2 * t] = rs0; cur[2 * t + 1] = rs1;
    if (p == NP - 1 && t == 0) row_start[N_NODES] = N_EDGES;
    __syncthreads();
    for (int r = t; r < cnt; r += 256) {
        uint2 rec = part_buf[beg + r];
        int slot = atomicAdd(&cur[rec.y & 511], 1);
        csr_src[slot] = (int)rec.x;
    }
}

// ---------------- node embedding: hb = bf16(x @ W_embed + b), 16 rows/block ----------------
__global__ void __launch_bounds__(256)
k_embed(const float* __restrict__ x, const float* __restrict__ W,
        const float* __restrict__ b, uint2* __restrict__ hb2) {
    __shared__ float Ws[F_IN * HD];      // 8 KB
    __shared__ float xs[16 * F_IN];      // 2 KB
    int t = threadIdx.x;
    int base = blockIdx.x * 16;
    for (int i = t; i < F_IN * HD; i += 256) Ws[i] = W[i];
    if (t < 128) {   // 16 rows x 8 float4
        int row = t >> 3, q4 = t & 7;
        int node = base + row;
        float4 v = {0.f, 0.f, 0.f, 0.f};
        if (node < N_NODES) v = ((const float4*)x)[node * 8 + q4];
        ((float4*)xs)[row * 8 + q4] = v;
    }
    __syncthreads();
    int r = t >> 4, q = t & 15;          // row r, cols 4q..4q+3
    float4 acc = ((const float4*)b)[q];
    const float* xr = xs + r * F_IN;
#pragma unroll
    for (int k = 0; k < F_IN; ++k) {
        float xv = xr[k];
        float4 wv = ((const float4*)(Ws + k * HD))[q];
        acc.x = fmaf(xv, wv.x, acc.x);
        acc.y = fmaf(xv, wv.y, acc.y);
        acc.z = fmaf(xv, wv.z, acc.z);
        acc.w = fmaf(xv, wv.w, acc.w);
    }
    int node = base + r;
    if (node < N_NODES) {
        uint2 o;
        o.x = pack2(acc.x, acc.y);
        o.y = pack2(acc.z, acc.w);
        hb2[node * 16 + q] = o;
    }
}

// ---------------- MFMA GEMM: Cf8[n] = fp8((relu(a*hb[n]+c) @ W) * dinv[n]) ----------------
__global__ void __launch_bounds__(256)
k_gemm_mfma(const unsigned* __restrict__ Ab, const float* __restrict__ W,
            const float* __restrict__ coef, const float* __restrict__ dinv,
            unsigned* __restrict__ Cf8) {
    __shared__ short Wt[64 * 72];
    __shared__ float Cs[4][16 * 66];
    int t = threadIdx.x;

    for (int i = t; i < HD * HD; i += 256) {
        int k = i >> 6, j = i & 63;
        Wt[j * 72 + k] = (short)bf16r(W[i]);
    }
    __syncthreads();

    int wid = t >> 6, lane = t & 63;
    int rlane = lane & 15, kb = lane >> 4;
    int base = blockIdx.x * 64 + wid * 16;
    int arow = base + rlane;
    if (arow > N_NODES - 1) arow = N_NODES - 1;
    bool has_coef = (coef != nullptr);

    short8v afrag[2];
#pragma unroll
    for (int h = 0; h < 2; ++h) {
        uint4 p = *reinterpret_cast<const uint4*>(Ab + arow * 32 + h * 16 + kb * 4);
        union { uint4 u; short8v s; } cv;
        if (has_coef) {
            int k0 = h * 32 + kb * 8;
            float v0 = unlo(p.x), v1 = unhi(p.x), v2 = unlo(p.y), v3 = unhi(p.y);
            float v4 = unlo(p.z), v5 = unhi(p.z), v6 = unlo(p.w), v7 = unhi(p.w);
            v0 = fmaxf(fmaf(coef[k0 + 0], v0, coef[64 + k0 + 0]), 0.f);
            v1 = fmaxf(fmaf(coef[k0 + 1], v1, coef[64 + k0 + 1]), 0.f);
            v2 = fmaxf(fmaf(coef[k0 + 2], v2, coef[64 + k0 + 2]), 0.f);
            v3 = fmaxf(fmaf(coef[k0 + 3], v3, coef[64 + k0 + 3]), 0.f);
            v4 = fmaxf(fmaf(coef[k0 + 4], v4, coef[64 + k0 + 4]), 0.f);
            v5 = fmaxf(fmaf(coef[k0 + 5], v5, coef[64 + k0 + 5]), 0.f);
            v6 = fmaxf(fmaf(coef[k0 + 6], v6, coef[64 + k0 + 6]), 0.f);
            v7 = fmaxf(fmaf(coef[k0 + 7], v7, coef[64 + k0 + 7]), 0.f);
            cv.u.x = pack2(v0, v1); cv.u.y = pack2(v2, v3);
            cv.u.z = pack2(v4, v5); cv.u.w = pack2(v6, v7);
        } else {
            cv.u = p;
        }
        afrag[h] = cv.s;
    }

    f32x4 acc[4];
#pragma unroll
    for (int nt = 0; nt < 4; ++nt) acc[nt] = (f32x4){0.f, 0.f, 0.f, 0.f};

#pragma unroll
    for (int nt = 0; nt < 4; ++nt) {
        int col = nt * 16 + rlane;
#pragma unroll
        for (int h = 0; h < 2; ++h) {
            short8v b = *reinterpret_cast<const short8v*>(&Wt[col * 72 + h * 32 + kb * 8]);
            acc[nt] = __builtin_amdgcn_mfma_f32_16x16x32_bf16(afrag[h], b, acc[nt], 0, 0, 0);
        }
    }

    float dv[4];
#pragma unroll
    for (int r = 0; r < 4; ++r) {
        int g = base + kb * 4 + r;
        dv[r] = dinv[g > N_NODES - 1 ? N_NODES - 1 : g];
    }
#pragma unroll
    for (int nt = 0; nt < 4; ++nt) {
        int col = nt * 16 + rlane;
#pragma unroll
        for (int r = 0; r < 4; ++r)
            Cs[wid][(kb * 4 + r) * 66 + col] = acc[nt][r] * dv[r];
    }
    __syncthreads();

#pragma unroll
    for (int u = 0; u < 4; ++u) {
        int o = u * 64 + lane;
        int row = o >> 4, q = o & 15;
        int node = blockIdx.x * 64 + wid * 16 + row;
        if (node < N_NODES) {
            const float* cp = &Cs[wid][row * 66 + q * 4];
            Cf8[node * 16 + q] = pack_fp8x4(cp[0], cp[1], cp[2], cp[3]);
        }
    }
}

// ---------------- CSR gather (fp8, 64B rows) + fused BN stats, 8-deep unroll ----------------
__global__ void __launch_bounds__(256)
k_gather_stats(const unsigned* __restrict__ xwf8, const int* __restrict__ row_start,
               const int* __restrict__ csr_src, const float* __restrict__ dinv,
               const float* __restrict__ cb, uint2* __restrict__ hb2,
               float* __restrict__ stats_sh) {
    int t = threadIdx.x;
    int q = t & 15;
    int r = t >> 4;
    float cb0 = cb[q * 4 + 0], cb1 = cb[q * 4 + 1];
    float cb2 = cb[q * 4 + 2], cb3 = cb[q * 4 + 3];
    float4 st_s = {0.f, 0.f, 0.f, 0.f}, st_q = {0.f, 0.f, 0.f, 0.f};

#pragma unroll
    for (int i = 0; i < 4; ++i) {
        int n = blockIdx.x * 64 + r * 4 + i;
        bool valid = (n < N_NODES);
        int beg = 0, end = 0;
        if (valid) { beg = row_start[n]; end = row_start[n + 1]; }
        float4 a0 = {0.f,0.f,0.f,0.f}, a1 = {0.f,0.f,0.f,0.f};
        float4 a2 = {0.f,0.f,0.f,0.f}, a3 = {0.f,0.f,0.f,0.f};
        if (valid) {
            unsigned p = xwf8[n * 16 + q];
            DECODE8(p, a0);
        }
        int e = beg;
        for (; e + 7 < end; e += 8) {
            int s0 = csr_src[e],     s1 = csr_src[e + 1];
            int s2 = csr_src[e + 2], s3 = csr_src[e + 3];
            int s4 = csr_src[e + 4], s5 = csr_src[e + 5];
            int s6 = csr_src[e + 6], s7 = csr_src[e + 7];
            unsigned p0 = xwf8[s0 * 16 + q], p1 = xwf8[s1 * 16 + q];
            unsigned p2 = xwf8[s2 * 16 + q], p3 = xwf8[s3 * 16 + q];
            unsigned p4 = xwf8[s4 * 16 + q], p5 = xwf8[s5 * 16 + q];
            unsigned p6 = xwf8[s6 * 16 + q], p7 = xwf8[s7 * 16 + q];
            DECODE8(p0, a0); DECODE8(p1, a1); DECODE8(p2, a2); DECODE8(p3, a3);
            DECODE8(p4, a0); DECODE8(p5, a1); DECODE8(p6, a2); DECODE8(p7, a3);
        }
        for (; e + 3 < end; e += 4) {
            int s0 = csr_src[e],     s1 = csr_src[e + 1];
            int s2 = csr_src[e + 2], s3 = csr_src[e + 3];
            unsigned p0 = xwf8[s0 * 16 + q], p1 = xwf8[s1 * 16 + q];
            unsigned p2 = xwf8[s2 * 16 + q], p3 = xwf8[s3 * 16 + q];
            DECODE8(p0, a0); DECODE8(p1, a1); DECODE8(p2, a2); DECODE8(p3, a3);
        }
        for (; e < end; ++e) {
            int s0 = csr_src[e];
            unsigned p0 = xwf8[s0 * 16 + q];
            DECODE8(p0, a0);
        }
        float dn = valid ? dinv[n] : 0.f;
        float4 h;
        h.x = fmaf(a0.x + a1.x + a2.x + a3.x, dn, cb0);
        h.y = fmaf(a0.y + a1.y + a2.y + a3.y, dn, cb1);
        h.z = fmaf(a0.z + a1.z + a2.z + a3.z, dn, cb2);
        h.w = fmaf(a0.w + a1.w + a2.w + a3.w, dn, cb3);
        if (valid) {
            uint2 o;
            o.x = pack2(h.x, h.y);
            o.y = pack2(h.z, h.w);
            hb2[n * 16 + q] = o;
            st_s.x += h.x; st_s.y += h.y; st_s.z += h.z; st_s.w += h.w;
            st_q.x = fmaf(h.x, h.x, st_q.x); st_q.y = fmaf(h.y, h.y, st_q.y);
            st_q.z = fmaf(h.z, h.z, st_q.z); st_q.w = fmaf(h.w, h.w, st_q.w);
        }
    }

    __shared__ float4 ls_s[256], ls_q[256];
    ls_s[t] = st_s; ls_q[t] = st_q;
    __syncthreads();
    if (t < 16) {
        float4 ss = ls_s[t], qq = ls_q[t];
        for (int rr = 1; rr < 16; ++rr) {
            float4 u = ls_s[rr * 16 + t], v = ls_q[rr * 16 + t];
            ss.x += u.x; ss.y += u.y; ss.z += u.z; ss.w += u.w;
            qq.x += v.x; qq.y += v.y; qq.z += v.z; qq.w += v.w;
        }
        float* sh = stats_sh + (blockIdx.x & (NSHADOW - 1)) * 128;
        atomicAdd(&sh[4 * t + 0], ss.x);
        atomicAdd(&sh[4 * t + 1], ss.y);
        atomicAdd(&sh[4 * t + 2], ss.z);
        atomicAdd(&sh[4 * t + 3], ss.w);
        atomicAdd(&sh[64 + 4 * t + 0], qq.x);
        atomicAdd(&sh[64 + 4 * t + 1], qq.y);
        atomicAdd(&sh[64 + 4 * t + 2], qq.z);
        atomicAdd(&sh[64 + 4 * t + 3], qq.w);
    }
}

// ---------------- shadow stats -> affine coef ----------------
__global__ void k_bn_coef(const float* __restrict__ stats_sh, const float* __restrict__ gamma,
                          const float* __restrict__ beta, float* __restrict__ coef) {
    int j = threadIdx.x;
    float s = 0.f, s2 = 0.f;
    for (int c = 0; c < NSHADOW; ++c) {
        s  += stats_sh[c * 128 + j];
        s2 += stats_sh[c * 128 + 64 + j];
    }
    float mu  = s * (1.0f / N_NODES);
    float var = s2 * (1.0f / N_NODES) - mu * mu;
    float rs  = rsqrtf(var + EPS);
    float a   = gamma[j] * rs;
    coef[j]      = a;
    coef[64 + j] = fmaf(-a, mu, beta[j]);
}

// ---------------- mean pool with fused BN+ReLU (bf16 h in) ----------------
__global__ void k_pool(const unsigned* __restrict__ hb, const float* __restrict__ coef,
                       float* __restrict__ pooled) {
    int t = threadIdx.x;
    int j = t & 63, rg = t >> 6;
    float a = coef[j], c = coef[64 + j];
    float s = 0.f;
    for (int n = blockIdx.x * 4 + rg; n < N_NODES; n += gridDim.x * 4) {
        unsigned p = hb[n * 32 + (j >> 1)];
        float v = (j & 1) ? unhi(p) : unlo(p);
        s += fmaxf(fmaf(a, v, c), 0.f);
    }
    __shared__ float ls[256];
    ls[t] = s;
    __syncthreads();
    if (t < 64)
        atomicAdd(&pooled[j], ls[t] + ls[t + 64] + ls[t + 128] + ls[t + 192]);
}

// ---------------- output ----------------
__global__ void k_out(const float* __restrict__ pooled, const float* __restrict__ Wout,
                      const float* __restrict__ bout, float* __restrict__ out) {
    int o = threadIdx.x;
    float acc = bout[o];
#pragma unroll
    for (int k = 0; k < HD; ++k)
        acc = fmaf(pooled[k] * (1.0f / N_NODES), Wout[k * HD + o], acc);
    out[o] = acc;
}

extern "C" void kernel_launch(void* const* d_in, const int* in_sizes, int n_in,
                              void* d_out, int out_size, void* d_ws, size_t ws_size,
                              hipStream_t stream) {
    const float* x        = (const float*)d_in[0];
    const int*   ei       = (const int*)  d_in[1];
    const float* W_embed  = (const float*)d_in[2];
    const float* b_embed  = (const float*)d_in[3];
    const float* conv_W   = (const float*)d_in[4];
    const float* conv_b   = (const float*)d_in[5];
    const float* bn_gamma = (const float*)d_in[6];
    const float* bn_beta  = (const float*)d_in[7];
    const float* W_out    = (const float*)d_in[8];
    const float* b_out    = (const float*)d_in[9];
    float* out = (float*)d_out;

    float* ws = (float*)d_ws;
    float* dinv      = ws;                                // N
    int*   row_start = (int*)(ws + N_NODES);              // N+1 (pad 8)
    float* small     = ws + 2 * N_NODES + 8;
    float* stats_sh  = small;                             // 4 layers * NSHADOW*128 = 32768
    float* pooled    = small + 32768;                     // 64
    float* coef      = small + 32832;                     // 4*128 = 512
    int*   flag      = (int*)(small + 33344);             // 1 (pad 64)
    int*   csr_src   = (int*)(small + 33408);             // E
    int*   hcnt      = (int*)(small + 33408 + N_EDGES);   // NP*NB1 = 49000
    int*   off_bp    = hcnt + NP * NB1;                   // 49000
    int*   ptotal    = off_bp + NP * NB1;                 // 256
    int*   pbase     = ptotal + 256;                      // 256
    uint2* part_buf  = (uint2*)(pbase + 256);             // E uint2 (12.8 MB)
    float* bufA      = (float*)(part_buf + N_EDGES);      // N*32 uints (bf16 h)
    float* bufB      = bufA + N_NODES * 32;               // N*16 uints (fp8 xw)

    k_detect<<<1, 64, 0, stream>>>(ei, flag);
    k_p1_hist<<<NB1, 256, 0, stream>>>(ei, flag, hcnt);
    k_p2scan<<<NP, 256, 0, stream>>>(hcnt, off_bp, ptotal);
    k_p3scan<<<1, 256, 0, stream>>>(ptotal, pbase);
    k_p2_scatter<<<NB1, 256, 0, stream>>>(ei, flag, off_bp, pbase, part_buf);
    k_p3_build<<<NP, 256, 0, stream>>>(part_buf, pbase, ptotal, row_start, dinv, csr_src);
    k_embed<<<(N_NODES + 15) / 16, 256, 0, stream>>>(x, W_embed, b_embed, (uint2*)bufA);
    hipMemsetAsync(stats_sh, 0, 4 * NSHADOW * 128 * sizeof(float), stream);

    for (int l = 0; l < 4; ++l) {
        float* st = stats_sh + l * NSHADOW * 128;
        k_gemm_mfma<<<(N_NODES + 63) / 64, 256, 0, stream>>>(
            (const unsigned*)bufA, conv_W + l * HD * HD,
            l ? coef + (l - 1) * 128 : nullptr, dinv, (unsigned*)bufB);
        k_gather_stats<<<(N_NODES + 63) / 64, 256, 0, stream>>>(
            (const unsigned*)bufB, row_start, csr_src, dinv, conv_b + l * HD,
            (uint2*)bufA, st);
        k_bn_coef<<<1, 64, 0, stream>>>(st, bn_gamma + l * HD, bn_beta + l * HD,
                                        coef + l * 128);
    }

    hipMemsetAsync(pooled, 0, 64 * sizeof(float), stream);
    k_pool<<<1024, 256, 0, stream>>>((const unsigned*)bufA, coef + 3 * 128, pooled);
    k_out<<<1, 64, 0, stream>>>(pooled, W_out, b_out, out);
}